// Round 13
// baseline (359.024 us; speedup 1.0000x reference)
//
#include <hip/hip_runtime.h>
#include <hip/hip_fp16.h>
#include <hip/hip_cooperative_groups.h>
#include <math.h>

namespace cg = cooperative_groups;

#define B_SZ   16
#define N_ATOM 286
#define NT     1024            // table entries, r_e = 3*e/(NT-1)
#define HIDW   150
#define FF_DIM 512
#define WPAD   152             // padded row length (38 float4)
#define WROWS  151             // 150 weight rows + 1 bias row

__device__ __forceinline__ float softplus_f(float x) {
  return fmaxf(x, 0.0f) + log1pf(expf(-fabsf(x)));
}
// torch Softplus(beta=5): softplus(5x)/5
__device__ __forceinline__ float sp5_f(float x) {
  float t = 5.0f * x;
  return (fmaxf(t, 0.0f) + log1pf(expf(-fabsf(t)))) * 0.2f;
}

__device__ __forceinline__ void cvt8(uint4 q, float* out) {
  const __half2* h = (const __half2*)&q;
  #pragma unroll
  for (int k = 0; k < 4; ++k) {
    float2 f = __half22float2(h[k]);
    out[2 * k] = f.x; out[2 * k + 1] = f.y;
  }
}

// ONE cooperative kernel, 256 blocks x 256 threads (1 block/CU), phases
// separated by grid.sync(). Eliminates 5 inter-kernel launch/drain gaps and
// keeps intermediates hot in L2 / clocks boosted.
__global__ __launch_bounds__(256) void fused_kernel(
    const float* __restrict__ xyz, const int* __restrict__ Z,
    const float* __restrict__ emb,
    const float* __restrict__ a_w0, const float* __restrict__ a_b0,
    const float* __restrict__ a_w1, const float* __restrict__ a_b1,
    const float* __restrict__ a_w2, const float* __restrict__ a_b2,
    const float* __restrict__ a_w3, const float* __restrict__ a_b3,
    const float* __restrict__ c_w0, const float* __restrict__ c_b0,
    const float* __restrict__ c_w1, const float* __restrict__ c_b1,
    const float* __restrict__ c_w2, const float* __restrict__ c_b2,
    const float* __restrict__ c_w3, const float* __restrict__ c_b3,
    const float* __restrict__ fc_w, const float* __restrict__ fc_b,
    const float* __restrict__ bn_g, const float* __restrict__ bn_b,
    const float* __restrict__ out_w, const float* __restrict__ out_b,
    float* __restrict__ out,
    float* __restrict__ Wp, float* __restrict__ f1, float* __restrict__ f2,
    float* __restrict__ pool_sq,
    __half* __restrict__ tabh0, __half* __restrict__ tabh1) {
  __shared__ float sA[WPAD * 8];   // 1216 floats, multi-purpose per phase
  __shared__ float sB[WPAD * 8];

  cg::grid_group grid = cg::this_grid();
  const int tid  = threadIdx.x;
  const int lane = tid & 63;
  const int wave = __builtin_amdgcn_readfirstlane(tid >> 6);

  // ================= Phase A: pack hidden weights [151][152] ==============
  {
    const int total = 4 * WROWS * WPAD;
    for (int idx = blockIdx.x * 256 + tid; idx < total; idx += 256 * 256) {
      int m  = idx / (WROWS * WPAD);
      int r2 = idx - m * (WROWS * WPAD);
      int i = r2 / WPAD, o = r2 - i * WPAD;
      const float* W  = (m == 0) ? a_w1 : (m == 1) ? a_w2 : (m == 2) ? c_w1 : c_w2;
      const float* Bb = (m == 0) ? a_b1 : (m == 1) ? a_b2 : (m == 2) ? c_b1 : c_b2;
      float v = 0.0f;
      if (o < HIDW) v = (i < HIDW) ? W[i * HIDW + o] : Bb[o];
      Wp[idx] = v;
    }
  }
  grid.sync();

  // ================= Phase B: radial-MLP table (both clouds) ==============
  {
    const int nblk = NT / 8;                       // 128 blocks per cloud
    const int cloud = (blockIdx.x >= nblk) ? 1 : 0;
    const int blk   = blockIdx.x - cloud * nblk;
    const float* w0 = cloud ? c_w0 : a_w0;  const float* b0 = cloud ? c_b0 : a_b0;
    const float* w3 = cloud ? c_w3 : a_w3;  const float* b3 = cloud ? c_b3 : a_b3;
    const float* __restrict__ Wp1 = Wp + (size_t)(cloud * 2)     * WROWS * WPAD;
    const float* __restrict__ Wp2 = Wp + (size_t)(cloud * 2 + 1) * WROWS * WPAD;
    __half* table = cloud ? tabh1 : tabh0;
    const int e0 = wave * 2;
    const int gbase = blk * 8;
    const int jj = (lane < 38) ? lane : 37;

    float x0[3], x1[3];
    #pragma unroll
    for (int k = 0; k < 3; ++k) {
      float r0 = 3.0f * (float)(gbase + e0)     / (float)(NT - 1);
      float r1 = 3.0f * (float)(gbase + e0 + 1) / (float)(NT - 1);
      float d0 = (r0 - 1.5f * (float)k) * (1.0f / 1.5f);
      float d1 = (r1 - 1.5f * (float)k) * (1.0f / 1.5f);
      float cc0 = cosf(1.57079632679489662f * d0);
      float cc1 = cosf(1.57079632679489662f * d1);
      x0[k] = (fabsf(d0) < 1.0f) ? cc0 * cc0 : 0.0f;
      x1[k] = (fabsf(d1) < 1.0f) ? cc1 * cc1 : 0.0f;
    }

    // layer 0: 3 -> 150 into sA
    #pragma unroll
    for (int c = 0; c < 3; ++c) {
      int o = lane + 64 * c;
      int oc = (o < HIDW) ? o : (HIDW - 1);
      float w00 = w0[oc], w01 = w0[HIDW + oc], w02 = w0[2 * HIDW + oc], bb = b0[oc];
      float h0 = sp5_f(bb + x0[0] * w00 + x0[1] * w01 + x0[2] * w02);
      float h1 = sp5_f(bb + x1[0] * w00 + x1[1] * w01 + x1[2] * w02);
      if (o < HIDW) *(float2*)(&sA[o * 8 + e0]) = make_float2(h0, h1);
    }
    // wave-private act columns: no barrier

    // layer 1: sA x Wp1 -> sB
    {
      const float* __restrict__ Wb = Wp1 + 4 * jj;
      float4 a0 = *(const float4*)(Wp1 + HIDW * WPAD + 4 * jj);
      float4 a1 = a0;
      #pragma unroll 10
      for (int i = 0; i < HIDW; ++i) {
        float4 wv = *(const float4*)(Wb + i * WPAD);
        float2 h  = *(const float2*)(&sA[i * 8 + e0]);
        a0.x = __builtin_fmaf(h.x, wv.x, a0.x); a1.x = __builtin_fmaf(h.y, wv.x, a1.x);
        a0.y = __builtin_fmaf(h.x, wv.y, a0.y); a1.y = __builtin_fmaf(h.y, wv.y, a1.y);
        a0.z = __builtin_fmaf(h.x, wv.z, a0.z); a1.z = __builtin_fmaf(h.y, wv.z, a1.z);
        a0.w = __builtin_fmaf(h.x, wv.w, a0.w); a1.w = __builtin_fmaf(h.y, wv.w, a1.w);
      }
      *(float2*)(&sB[(4 * jj + 0) * 8 + e0]) = make_float2(sp5_f(a0.x), sp5_f(a1.x));
      *(float2*)(&sB[(4 * jj + 1) * 8 + e0]) = make_float2(sp5_f(a0.y), sp5_f(a1.y));
      *(float2*)(&sB[(4 * jj + 2) * 8 + e0]) = make_float2(sp5_f(a0.z), sp5_f(a1.z));
      *(float2*)(&sB[(4 * jj + 3) * 8 + e0]) = make_float2(sp5_f(a0.w), sp5_f(a1.w));
    }
    // layer 2: sB x Wp2 -> sA
    {
      const float* __restrict__ Wb = Wp2 + 4 * jj;
      float4 a0 = *(const float4*)(Wp2 + HIDW * WPAD + 4 * jj);
      float4 a1 = a0;
      #pragma unroll 10
      for (int i = 0; i < HIDW; ++i) {
        float4 wv = *(const float4*)(Wb + i * WPAD);
        float2 h  = *(const float2*)(&sB[i * 8 + e0]);
        a0.x = __builtin_fmaf(h.x, wv.x, a0.x); a1.x = __builtin_fmaf(h.y, wv.x, a1.x);
        a0.y = __builtin_fmaf(h.x, wv.y, a0.y); a1.y = __builtin_fmaf(h.y, wv.y, a1.y);
        a0.z = __builtin_fmaf(h.x, wv.z, a0.z); a1.z = __builtin_fmaf(h.y, wv.z, a1.z);
        a0.w = __builtin_fmaf(h.x, wv.w, a0.w); a1.w = __builtin_fmaf(h.y, wv.w, a1.w);
      }
      *(float2*)(&sA[(4 * jj + 0) * 8 + e0]) = make_float2(sp5_f(a0.x), sp5_f(a1.x));
      *(float2*)(&sA[(4 * jj + 1) * 8 + e0]) = make_float2(sp5_f(a0.y), sp5_f(a1.y));
      *(float2*)(&sA[(4 * jj + 2) * 8 + e0]) = make_float2(sp5_f(a0.z), sp5_f(a1.z));
      *(float2*)(&sA[(4 * jj + 3) * 8 + e0]) = make_float2(sp5_f(a0.w), sp5_f(a1.w));
    }
    // layer 3: 150 -> 16
    {
      const int o  = lane & 15;
      const int ig = lane >> 4;
      float a0 = 0.f, a1 = 0.f;
      for (int i = ig; i < HIDW; i += 4) {
        float wv = w3[i * 16 + o];
        float h0 = sA[i * 8 + e0];
        float h1 = sA[i * 8 + e0 + 1];
        a0 = __builtin_fmaf(h0, wv, a0);
        a1 = __builtin_fmaf(h1, wv, a1);
      }
      a0 += __shfl_xor(a0, 16, 64); a0 += __shfl_xor(a0, 32, 64);
      a1 += __shfl_xor(a1, 16, 64); a1 += __shfl_xor(a1, 32, 64);
      if (lane < 16) {
        float bb = b3[o];
        table[(size_t)(gbase + e0)     * 16 + o] = __float2half(a0 + bb);
        table[(size_t)(gbase + e0 + 1) * 16 + o] = __float2half(a1 + bb);
      }
    }
  }
  grid.sync();

  // ================= Phases C/D: the two cloud convolutions ==============
  // 16 blocks per z; each block stages coords+feats once, computes 18 rows.
  {
    const int z   = blockIdx.x >> 4;
    const int sub = blockIdx.x & 15;
    const int a0r = sub * 18;
    const int a1r = (a0r + 18 < N_ATOM) ? a0r + 18 : N_ATOM;

    for (int pass = 0; pass < 2; ++pass) {
      const __half* __restrict__ tabh = pass ? tabh1 : tabh0;
      float* __restrict__ fout = pass ? f2 : f1;

      // stage coords (sA) + features (sB), SoA
      for (int b = tid; b < N_ATOM; b += 256) {
        const float* p = xyz + ((size_t)z * N_ATOM + b) * 3;
        sA[b] = p[0]; sA[304 + b] = p[1]; sA[608 + b] = p[2];
        float4 fb;
        if (pass == 0) {
          int zi = Z[z * N_ATOM + b];
          fb = *(const float4*)(emb + (size_t)zi * 4);
        } else {
          fb = *(const float4*)(f1 + ((size_t)z * N_ATOM + b) * 4);
        }
        sB[b] = fb.x; sB[304 + b] = fb.y; sB[608 + b] = fb.z; sB[912 + b] = fb.w;
      }
      __syncthreads();

      for (int row = a0r + wave; row < a1r; row += 4) {
        const float ax = sA[row], ay = sA[304 + row], az = sA[608 + row];
        float acc[4] = {0.f, 0.f, 0.f, 0.f};
        float cnt = 0.f;
        for (int b = lane; b < N_ATOM; b += 64) {
          float dx = ax - sA[b], dy = ay - sA[304 + b], dz = az - sA[608 + b];
          float r = sqrtf(dx * dx + dy * dy + dz * dz + 1e-12f);
          float msk = (r < 3.0f) ? 1.0f : 0.0f;
          float t = r * ((float)(NT - 1) / 3.0f);
          int idx = (int)t;
          if (idx > NT - 2) idx = NT - 2;
          float fr = t - (float)idx;
          const uint4* Tp = (const uint4*)(tabh + (size_t)idx * 16);
          uint4 q0 = Tp[0], q1 = Tp[1], q2 = Tp[2], q3 = Tp[3];
          float fbx = sB[b], fby = sB[304 + b], fbz = sB[608 + b], fbw = sB[912 + b];
          cnt += msk;
          float r0[16], r1[16];
          cvt8(q0, r0); cvt8(q1, r0 + 8);
          cvt8(q2, r1); cvt8(q3, r1 + 8);
          #pragma unroll
          for (int i = 0; i < 4; ++i) {
            float v0 = r0[4 * i + 0] + fr * (r1[4 * i + 0] - r0[4 * i + 0]);
            float v1 = r0[4 * i + 1] + fr * (r1[4 * i + 1] - r0[4 * i + 1]);
            float v2 = r0[4 * i + 2] + fr * (r1[4 * i + 2] - r0[4 * i + 2]);
            float v3 = r0[4 * i + 3] + fr * (r1[4 * i + 3] - r0[4 * i + 3]);
            acc[i] = __builtin_fmaf(msk, v0 * fbx + v1 * fby + v2 * fbz + v3 * fbw,
                                    acc[i]);
          }
        }
        #pragma unroll
        for (int m = 32; m > 0; m >>= 1) {
          #pragma unroll
          for (int i = 0; i < 4; ++i) acc[i] += __shfl_xor(acc[i], m, 64);
          cnt += __shfl_xor(cnt, m, 64);
        }
        if (lane == 0) {
          float nb = cnt < 1.0f ? 1.0f : cnt;
          float sc = 1.0f / sqrtf(nb);
          float4 o;
          o.x = acc[0] * sc; o.y = acc[1] * sc; o.z = acc[2] * sc; o.w = acc[3] * sc;
          *(float4*)(fout + ((size_t)z * N_ATOM + row) * 4) = o;
        }
      }
      grid.sync();   // pass-0 results visible device-wide before pass 1
    }
  }

  // ================= Phase E: L2-pool (blocks 0..15) =====================
  if (blockIdx.x < B_SZ) {
    const int z = blockIdx.x;
    float s[8] = {0.f, 0.f, 0.f, 0.f, 0.f, 0.f, 0.f, 0.f};
    for (int a = tid; a < N_ATOM; a += 256) {
      float4 v1 = *(const float4*)(f1 + ((size_t)z * N_ATOM + a) * 4);
      float4 v2 = *(const float4*)(f2 + ((size_t)z * N_ATOM + a) * 4);
      s[0] += v1.x * v1.x; s[1] += v1.y * v1.y;
      s[2] += v1.z * v1.z; s[3] += v1.w * v1.w;
      s[4] += v2.x * v2.x; s[5] += v2.y * v2.y;
      s[6] += v2.z * v2.z; s[7] += v2.w * v2.w;
    }
    #pragma unroll
    for (int m = 32; m > 0; m >>= 1) {
      #pragma unroll
      for (int k = 0; k < 8; ++k) s[k] += __shfl_xor(s[k], m, 64);
    }
    if (lane == 0) {
      #pragma unroll
      for (int k = 0; k < 8; ++k) sB[wave * 8 + k] = s[k];
    }
    __syncthreads();
    if (tid < 8)
      pool_sq[z * 8 + tid] = sB[tid] + sB[8 + tid] + sB[16 + tid] + sB[24 + tid];
  }
  grid.sync();

  // ================= Phase F: FC/BN/out (block 0) ========================
  if (blockIdx.x == 0) {
    if (tid < 128) sA[tid] = sqrtf(pool_sq[tid]);   // pooled[z][c] = sA[z*8+c]
    __syncthreads();
    float acc16[16];
    #pragma unroll
    for (int zz = 0; zz < 16; ++zz) acc16[zz] = 0.f;
    #pragma unroll
    for (int ff = 0; ff < 2; ++ff) {
      const int f = tid + ff * 256;
      float hv[16];
      float mean = 0.f;
      #pragma unroll
      for (int zz = 0; zz < 16; ++zz) {
        float a = fc_b[f];
        #pragma unroll
        for (int c = 0; c < 8; ++c) a += sA[zz * 8 + c] * fc_w[c * FF_DIM + f];
        hv[zz] = softplus_f(a);
        mean += hv[zz];
      }
      mean *= (1.0f / 16.0f);
      float var = 0.f;
      #pragma unroll
      for (int zz = 0; zz < 16; ++zz) { float d = hv[zz] - mean; var += d * d; }
      var *= (1.0f / 16.0f);
      float istd = 1.0f / sqrtf(var + 1e-5f);
      float g = bn_g[f], bb = bn_b[f], ow = out_w[f];
      #pragma unroll
      for (int zz = 0; zz < 16; ++zz)
        acc16[zz] += softplus_f((hv[zz] - mean) * istd * g + bb) * ow;
    }
    #pragma unroll
    for (int m = 32; m > 0; m >>= 1) {
      #pragma unroll
      for (int zz = 0; zz < 16; ++zz) acc16[zz] += __shfl_xor(acc16[zz], m, 64);
    }
    if (lane == 0) {
      #pragma unroll
      for (int zz = 0; zz < 16; ++zz) sA[128 + wave * 16 + zz] = acc16[zz];
    }
    __syncthreads();
    if (tid < 16) {
      float s = out_b[0] + sA[128 + tid] + sA[144 + tid] + sA[160 + tid]
                         + sA[176 + tid];
      out[tid] = 1.0f / (1.0f + expf(-s));
    }
  }
}

extern "C" void kernel_launch(void* const* d_in, const int* in_sizes, int n_in,
                              void* d_out, int out_size, void* d_ws, size_t ws_size,
                              hipStream_t stream) {
  const float* xyz = (const float*)d_in[0];
  const int*   Z   = (const int*)d_in[1];
  const float* emb = (const float*)d_in[2];
  const float* a_w0 = (const float*)d_in[3];  const float* a_b0 = (const float*)d_in[4];
  const float* a_w1 = (const float*)d_in[5];  const float* a_b1 = (const float*)d_in[6];
  const float* a_w2 = (const float*)d_in[7];  const float* a_b2 = (const float*)d_in[8];
  const float* a_w3 = (const float*)d_in[9];  const float* a_b3 = (const float*)d_in[10];
  const float* c_w0 = (const float*)d_in[11]; const float* c_b0 = (const float*)d_in[12];
  const float* c_w1 = (const float*)d_in[13]; const float* c_b1 = (const float*)d_in[14];
  const float* c_w2 = (const float*)d_in[15]; const float* c_b2 = (const float*)d_in[16];
  const float* c_w3 = (const float*)d_in[17]; const float* c_b3 = (const float*)d_in[18];
  const float* fc_w  = (const float*)d_in[19];
  const float* fc_b  = (const float*)d_in[20];
  const float* bn_g  = (const float*)d_in[21];
  const float* bn_b  = (const float*)d_in[22];
  const float* out_w = (const float*)d_in[23];
  const float* out_b = (const float*)d_in[24];
  float* out = (float*)d_out;

  float* wsf = (float*)d_ws;
  float* Wp = wsf;                                             // 4*151*152 f32
  float* f1 = Wp + (size_t)4 * WROWS * WPAD;                   // 16*286*4 f32
  float* f2 = f1 + (size_t)B_SZ * N_ATOM * 4;
  float* pool_sq = f2 + (size_t)B_SZ * N_ATOM * 4;             // 128 f32
  __half* tabh0 = (__half*)(pool_sq + 128);                    // NT*16 f16
  __half* tabh1 = tabh0 + (size_t)NT * 16;

  void* params[] = {
    (void*)&xyz, (void*)&Z, (void*)&emb,
    (void*)&a_w0, (void*)&a_b0, (void*)&a_w1, (void*)&a_b1,
    (void*)&a_w2, (void*)&a_b2, (void*)&a_w3, (void*)&a_b3,
    (void*)&c_w0, (void*)&c_b0, (void*)&c_w1, (void*)&c_b1,
    (void*)&c_w2, (void*)&c_b2, (void*)&c_w3, (void*)&c_b3,
    (void*)&fc_w, (void*)&fc_b, (void*)&bn_g, (void*)&bn_b,
    (void*)&out_w, (void*)&out_b, (void*)&out,
    (void*)&Wp, (void*)&f1, (void*)&f2, (void*)&pool_sq,
    (void*)&tabh0, (void*)&tabh1
  };
  hipLaunchCooperativeKernel((void*)fused_kernel, dim3(256), dim3(256),
                             params, 0, stream);
}

// Round 15
// 165.992 us; speedup vs baseline: 2.1629x; 2.1629x over previous
//
#include <hip/hip_runtime.h>
#include <hip/hip_fp16.h>
#include <math.h>

#define B_SZ   16
#define N_ATOM 286
#define NT     1024            // table entries, r_e = 3*e/(NT-1)
#define HIDW   150
#define FF_DIM 512
#define BLK_PER_Z 72           // conv blocks per batch element (72*4=288 rows)

__device__ __forceinline__ float softplus_f(float x) {
  return fmaxf(x, 0.0f) + log1pf(expf(-fabsf(x)));
}
// torch Softplus(beta=5): softplus(5x)/5
__device__ __forceinline__ float sp5_f(float x) {
  float t = 5.0f * x;
  return (fmaxf(t, 0.0f) + log1pf(expf(-fabsf(t)))) * 0.2f;
}

// Tabulate radial MLP R(r), both clouds. Grid = 2*(NT/2) = 1024 blocks
// (4 blocks/CU -> 4 waves/SIMD for latency hiding). Block = 4 waves handles
// 2 entries; waves SPLIT THE i-REDUCTION (38 rows each), partials combined
// in LDS. Weights read raw (no packing): row i col 4jj via two aligned
// float2 loads (i*150+4jj is even -> 8B-aligned).
__global__ __launch_bounds__(256) void table_kernel(
    const float* __restrict__ a_w0, const float* __restrict__ a_b0,
    const float* __restrict__ a_w1, const float* __restrict__ a_b1,
    const float* __restrict__ a_w2, const float* __restrict__ a_b2,
    const float* __restrict__ a_w3, const float* __restrict__ a_b3,
    const float* __restrict__ c_w0, const float* __restrict__ c_b0,
    const float* __restrict__ c_w1, const float* __restrict__ c_b1,
    const float* __restrict__ c_w2, const float* __restrict__ c_b2,
    const float* __restrict__ c_w3, const float* __restrict__ c_b3,
    __half* __restrict__ tabh0, __half* __restrict__ tabh1) {
  __shared__ float actA[304];        // [o*2 + e]
  __shared__ float actB[304];
  __shared__ float part[4 * 304];    // [wave][o*2 + e] partials

  const int nblk = NT / 2;                        // 512 blocks per cloud
  const int cloud = (blockIdx.x >= nblk) ? 1 : 0;
  const int blk   = blockIdx.x - cloud * nblk;
  const float* w0 = cloud ? c_w0 : a_w0;  const float* b0 = cloud ? c_b0 : a_b0;
  const float* w1 = cloud ? c_w1 : a_w1;  const float* b1 = cloud ? c_b1 : a_b1;
  const float* w2 = cloud ? c_w2 : a_w2;  const float* b2 = cloud ? c_b2 : a_b2;
  const float* w3 = cloud ? c_w3 : a_w3;  const float* b3 = cloud ? c_b3 : a_b3;
  __half* table = cloud ? tabh1 : tabh0;

  const int tid  = threadIdx.x;
  const int lane = tid & 63;
  const int wave = __builtin_amdgcn_readfirstlane(tid >> 6);
  const int gbase = blk * 2;                      // 2 entries per block

  // wave's reduction range over i
  const int i0 = wave * 38;
  const int i1 = (i0 + 38 < HIDW) ? i0 + 38 : HIDW;
  const int jj = (lane < 38) ? lane : 37;         // column group (4 cols)
  const int cA = 4 * jj;                          // cols cA, cA+1
  const int cB = (cA + 2 < HIDW) ? cA + 2 : 148;  // cols cB, cB+1 (clamped)

  // ---- layer 0: 3 -> 150, one output per thread (tid<150), both entries --
  if (tid < HIDW) {
    float w00 = w0[tid], w01 = w0[HIDW + tid], w02 = w0[2 * HIDW + tid];
    float bb = b0[tid];
    #pragma unroll
    for (int e = 0; e < 2; ++e) {
      float r = 3.0f * (float)(gbase + e) / (float)(NT - 1);
      float acc = bb;
      #pragma unroll
      for (int k = 0; k < 3; ++k) {
        float d = (r - 1.5f * (float)k) * (1.0f / 1.5f);
        float c = cosf(1.57079632679489662f * d);
        float x = (fabsf(d) < 1.0f) ? c * c : 0.0f;
        acc += x * ((k == 0) ? w00 : (k == 1) ? w01 : w02);
      }
      actA[tid * 2 + e] = sp5_f(acc);
    }
  }
  __syncthreads();

  // ---- layer 1: partial dot over [i0,i1), combine, sp5 -> actB ----------
  {
    float a00 = 0.f, a01 = 0.f, a10 = 0.f, a11 = 0.f;
    float a20 = 0.f, a21 = 0.f, a30 = 0.f, a31 = 0.f;
    #pragma unroll 4
    for (int i = i0; i < i1; ++i) {
      float2 wA = *(const float2*)(w1 + i * HIDW + cA);
      float2 wB = *(const float2*)(w1 + i * HIDW + cB);
      float2 h  = *(const float2*)(&actA[i * 2]);
      a00 = __builtin_fmaf(h.x, wA.x, a00); a01 = __builtin_fmaf(h.y, wA.x, a01);
      a10 = __builtin_fmaf(h.x, wA.y, a10); a11 = __builtin_fmaf(h.y, wA.y, a11);
      a20 = __builtin_fmaf(h.x, wB.x, a20); a21 = __builtin_fmaf(h.y, wB.x, a21);
      a30 = __builtin_fmaf(h.x, wB.y, a30); a31 = __builtin_fmaf(h.y, wB.y, a31);
    }
    if (lane < 38) {
      float* p = &part[wave * 304];
      *(float2*)(&p[(cA + 0) * 2]) = make_float2(a00, a01);
      *(float2*)(&p[(cA + 1) * 2]) = make_float2(a10, a11);
      if (jj < 37) {
        *(float2*)(&p[(cB + 0) * 2]) = make_float2(a20, a21);
        *(float2*)(&p[(cB + 1) * 2]) = make_float2(a30, a31);
      }
    }
  }
  __syncthreads();
  if (tid < HIDW) {
    float bb = b1[tid];
    #pragma unroll
    for (int e = 0; e < 2; ++e) {
      float v = bb + part[0 * 304 + tid * 2 + e] + part[1 * 304 + tid * 2 + e]
                   + part[2 * 304 + tid * 2 + e] + part[3 * 304 + tid * 2 + e];
      actB[tid * 2 + e] = sp5_f(v);
    }
  }
  __syncthreads();

  // ---- layer 2: same with w2, actB -> actA ------------------------------
  {
    float a00 = 0.f, a01 = 0.f, a10 = 0.f, a11 = 0.f;
    float a20 = 0.f, a21 = 0.f, a30 = 0.f, a31 = 0.f;
    #pragma unroll 4
    for (int i = i0; i < i1; ++i) {
      float2 wA = *(const float2*)(w2 + i * HIDW + cA);
      float2 wB = *(const float2*)(w2 + i * HIDW + cB);
      float2 h  = *(const float2*)(&actB[i * 2]);
      a00 = __builtin_fmaf(h.x, wA.x, a00); a01 = __builtin_fmaf(h.y, wA.x, a01);
      a10 = __builtin_fmaf(h.x, wA.y, a10); a11 = __builtin_fmaf(h.y, wA.y, a11);
      a20 = __builtin_fmaf(h.x, wB.x, a20); a21 = __builtin_fmaf(h.y, wB.x, a21);
      a30 = __builtin_fmaf(h.x, wB.y, a30); a31 = __builtin_fmaf(h.y, wB.y, a31);
    }
    if (lane < 38) {
      float* p = &part[wave * 304];
      *(float2*)(&p[(cA + 0) * 2]) = make_float2(a00, a01);
      *(float2*)(&p[(cA + 1) * 2]) = make_float2(a10, a11);
      if (jj < 37) {
        *(float2*)(&p[(cB + 0) * 2]) = make_float2(a20, a21);
        *(float2*)(&p[(cB + 1) * 2]) = make_float2(a30, a31);
      }
    }
  }
  __syncthreads();
  if (tid < HIDW) {
    float bb = b2[tid];
    #pragma unroll
    for (int e = 0; e < 2; ++e) {
      float v = bb + part[0 * 304 + tid * 2 + e] + part[1 * 304 + tid * 2 + e]
                   + part[2 * 304 + tid * 2 + e] + part[3 * 304 + tid * 2 + e];
      actA[tid * 2 + e] = sp5_f(v);
    }
  }
  __syncthreads();

  // ---- layer 3: 150 -> 16, i-split across waves + 4-group lanes ---------
  {
    const int o  = lane & 15;
    const int ig = lane >> 4;
    float p0 = 0.f, p1 = 0.f;
    for (int i = i0 + ig; i < i1; i += 4) {
      float wv = w3[i * 16 + o];
      float h0 = actA[i * 2 + 0];
      float h1 = actA[i * 2 + 1];
      p0 = __builtin_fmaf(h0, wv, p0);
      p1 = __builtin_fmaf(h1, wv, p1);
    }
    p0 += __shfl_xor(p0, 16, 64); p0 += __shfl_xor(p0, 32, 64);
    p1 += __shfl_xor(p1, 16, 64); p1 += __shfl_xor(p1, 32, 64);
    if (lane < 16) {
      part[wave * 32 + lane * 2 + 0] = p0;
      part[wave * 32 + lane * 2 + 1] = p1;
    }
  }
  __syncthreads();
  if (tid < 32) {
    int o = tid >> 1, e = tid & 1;
    float v = b3[o] + part[0 * 32 + o * 2 + e] + part[1 * 32 + o * 2 + e]
                    + part[2 * 32 + o * 2 + e] + part[3 * 32 + o * 2 + e];
    table[(size_t)(gbase + e) * 16 + o] = __float2half(v);
  }
}

__device__ __forceinline__ void cvt8(uint4 q, float* out) {
  const __half2* h = (const __half2*)&q;
  #pragma unroll
  for (int k = 0; k < 4; ++k) {
    float2 f = __half22float2(h[k]);
    out[2 * k] = f.x; out[2 * k + 1] = f.y;
  }
}

// Conv: grid = 16 z * 72 blocks, 4 rows per block (one per wave), all same z.
// Coordinates + input features staged in LDS (SoA, conflict-free) once per
// block. Neighbor loop is BRANCHLESS (multiply-mask) so the 4 table gathers
// are unconditional and pipeline. fp16 table lerp pair = 64 contiguous B.
__global__ __launch_bounds__(256) void conv_kernel(
    const float* __restrict__ xyz, const int* __restrict__ Z,
    const float* __restrict__ emb, const float* __restrict__ feats_in,
    const __half* __restrict__ tabh, float* __restrict__ f_out, int gather) {
  __shared__ float xs[N_ATOM], ys[N_ATOM], zs[N_ATOM];
  __shared__ float fxs[N_ATOM], fys[N_ATOM], fzs[N_ATOM], fws[N_ATOM];
  const int tid  = threadIdx.x;
  const int wave = tid >> 6;
  const int lane = tid & 63;
  const int z = blockIdx.x / BLK_PER_Z;
  const int a = (blockIdx.x % BLK_PER_Z) * 4 + wave;

  for (int b = tid; b < N_ATOM; b += 256) {
    const float* p = xyz + ((size_t)z * N_ATOM + b) * 3;
    xs[b] = p[0]; ys[b] = p[1]; zs[b] = p[2];
    float4 fb;
    if (gather) {
      int zi = Z[z * N_ATOM + b];
      fb = *(const float4*)(emb + (size_t)zi * 4);
    } else {
      fb = *(const float4*)(feats_in + ((size_t)z * N_ATOM + b) * 4);
    }
    fxs[b] = fb.x; fys[b] = fb.y; fzs[b] = fb.z; fws[b] = fb.w;
  }
  __syncthreads();
  if (a >= N_ATOM) return;

  const float ax = xs[a], ay = ys[a], az = zs[a];

  float acc[4] = {0.f, 0.f, 0.f, 0.f};
  float cnt = 0.f;
  for (int b = lane; b < N_ATOM; b += 64) {
    float dx = ax - xs[b], dy = ay - ys[b], dz = az - zs[b];
    float r = sqrtf(dx * dx + dy * dy + dz * dz + 1e-12f);
    float msk = (r < 3.0f) ? 1.0f : 0.0f;
    float t = r * ((float)(NT - 1) / 3.0f);
    int idx = (int)t;
    if (idx > NT - 2) idx = NT - 2;
    float fr = t - (float)idx;
    const uint4* Tp = (const uint4*)(tabh + (size_t)idx * 16);
    uint4 q0 = Tp[0], q1 = Tp[1], q2 = Tp[2], q3 = Tp[3];
    float fbx = fxs[b], fby = fys[b], fbz = fzs[b], fbw = fws[b];
    cnt += msk;
    float r0[16], r1[16];
    cvt8(q0, r0); cvt8(q1, r0 + 8);
    cvt8(q2, r1); cvt8(q3, r1 + 8);
    #pragma unroll
    for (int i = 0; i < 4; ++i) {
      float v0 = r0[4 * i + 0] + fr * (r1[4 * i + 0] - r0[4 * i + 0]);
      float v1 = r0[4 * i + 1] + fr * (r1[4 * i + 1] - r0[4 * i + 1]);
      float v2 = r0[4 * i + 2] + fr * (r1[4 * i + 2] - r0[4 * i + 2]);
      float v3 = r0[4 * i + 3] + fr * (r1[4 * i + 3] - r0[4 * i + 3]);
      acc[i] = __builtin_fmaf(msk, v0 * fbx + v1 * fby + v2 * fbz + v3 * fbw,
                              acc[i]);
    }
  }
  #pragma unroll
  for (int m = 32; m > 0; m >>= 1) {
    #pragma unroll
    for (int i = 0; i < 4; ++i) acc[i] += __shfl_xor(acc[i], m, 64);
    cnt += __shfl_xor(cnt, m, 64);
  }
  if (lane == 0) {
    float nb = cnt < 1.0f ? 1.0f : cnt;
    float sc = 1.0f / sqrtf(nb);
    float4 o;
    o.x = acc[0] * sc; o.y = acc[1] * sc; o.z = acc[2] * sc; o.w = acc[3] * sc;
    *(float4*)(f_out + ((size_t)z * N_ATOM + a) * 4) = o;
  }
}

// Parallel L2-pool: block z reduces sum of squares over atoms for all 8
// channels (4 from f1, 4 from f2). Coalesced float4 loads, shfl reduce.
__global__ __launch_bounds__(256) void pool_kernel(
    const float* __restrict__ f1, const float* __restrict__ f2,
    float* __restrict__ pool_sq) {
  __shared__ float red[4][8];
  const int z = blockIdx.x;
  const int tid = threadIdx.x;
  const int lane = tid & 63, wave = tid >> 6;
  float s[8] = {0.f, 0.f, 0.f, 0.f, 0.f, 0.f, 0.f, 0.f};
  for (int a = tid; a < N_ATOM; a += 256) {
    float4 v1 = *(const float4*)(f1 + ((size_t)z * N_ATOM + a) * 4);
    float4 v2 = *(const float4*)(f2 + ((size_t)z * N_ATOM + a) * 4);
    s[0] += v1.x * v1.x; s[1] += v1.y * v1.y;
    s[2] += v1.z * v1.z; s[3] += v1.w * v1.w;
    s[4] += v2.x * v2.x; s[5] += v2.y * v2.y;
    s[6] += v2.z * v2.z; s[7] += v2.w * v2.w;
  }
  #pragma unroll
  for (int m = 32; m > 0; m >>= 1) {
    #pragma unroll
    for (int k = 0; k < 8; ++k) s[k] += __shfl_xor(s[k], m, 64);
  }
  if (lane == 0) {
    #pragma unroll
    for (int k = 0; k < 8; ++k) red[wave][k] = s[k];
  }
  __syncthreads();
  if (tid < 8)
    pool_sq[z * 8 + tid] = red[0][tid] + red[1][tid] + red[2][tid] + red[3][tid];
}

// FC(8->512)+softplus -> batchnorm over B -> softplus -> FC(512->1) ->
// sigmoid. Pooling pre-reduced into pool_sq by pool_kernel.
__global__ __launch_bounds__(512) void tail_kernel(
    const float* __restrict__ pool_sq,
    const float* __restrict__ fc_w, const float* __restrict__ fc_b,
    const float* __restrict__ bn_g, const float* __restrict__ bn_b,
    const float* __restrict__ out_w, const float* __restrict__ out_b,
    float* __restrict__ out) {
  __shared__ float pooled[16][8];
  __shared__ float part[8][16];
  const int tid = threadIdx.x;

  if (tid < 128) pooled[tid >> 3][tid & 7] = sqrtf(pool_sq[tid]);
  __syncthreads();

  const int f = tid;
  float hv[16];
  float mean = 0.f;
  #pragma unroll
  for (int z = 0; z < 16; ++z) {
    float a = fc_b[f];
    #pragma unroll
    for (int c = 0; c < 8; ++c) a += pooled[z][c] * fc_w[c * FF_DIM + f];
    hv[z] = softplus_f(a);
    mean += hv[z];
  }
  mean *= (1.0f / 16.0f);
  float var = 0.f;
  #pragma unroll
  for (int z = 0; z < 16; ++z) { float d = hv[z] - mean; var += d * d; }
  var *= (1.0f / 16.0f);
  float istd = 1.0f / sqrtf(var + 1e-5f);
  float g = bn_g[f], bb = bn_b[f], ow = out_w[f];
  float contrib[16];
  #pragma unroll
  for (int z = 0; z < 16; ++z)
    contrib[z] = softplus_f((hv[z] - mean) * istd * g + bb) * ow;

  const int lane = tid & 63, wv = tid >> 6;
  #pragma unroll
  for (int m = 32; m > 0; m >>= 1) {
    #pragma unroll
    for (int z = 0; z < 16; ++z) contrib[z] += __shfl_xor(contrib[z], m, 64);
  }
  if (lane == 0) {
    #pragma unroll
    for (int z = 0; z < 16; ++z) part[wv][z] = contrib[z];
  }
  __syncthreads();
  if (tid < 16) {
    float s = out_b[0];
    #pragma unroll
    for (int w8 = 0; w8 < 8; ++w8) s += part[w8][tid];
    out[tid] = 1.0f / (1.0f + expf(-s));
  }
}

extern "C" void kernel_launch(void* const* d_in, const int* in_sizes, int n_in,
                              void* d_out, int out_size, void* d_ws, size_t ws_size,
                              hipStream_t stream) {
  const float* xyz = (const float*)d_in[0];
  const int*   Z   = (const int*)d_in[1];
  const float* emb = (const float*)d_in[2];
  const float* c0[8]; const float* c1[8];
  for (int i = 0; i < 8; ++i) {
    c0[i] = (const float*)d_in[3 + i];
    c1[i] = (const float*)d_in[11 + i];
  }
  const float* fc_w  = (const float*)d_in[19];
  const float* fc_b  = (const float*)d_in[20];
  const float* bn_g  = (const float*)d_in[21];
  const float* bn_b  = (const float*)d_in[22];
  const float* out_w = (const float*)d_in[23];
  const float* out_b = (const float*)d_in[24];
  float* out = (float*)d_out;

  float* wsf = (float*)d_ws;
  float* f1 = wsf;                                             // 16*286*4 f32
  float* f2 = f1 + (size_t)B_SZ * N_ATOM * 4;
  float* pool_sq = f2 + (size_t)B_SZ * N_ATOM * 4;             // 128 f32
  __half* tabh0 = (__half*)(pool_sq + 128);                    // NT*16 f16
  __half* tabh1 = tabh0 + (size_t)NT * 16;

  table_kernel<<<2 * (NT / 2), 256, 0, stream>>>(
      c0[0], c0[1], c0[2], c0[3], c0[4], c0[5], c0[6], c0[7],
      c1[0], c1[1], c1[2], c1[3], c1[4], c1[5], c1[6], c1[7],
      tabh0, tabh1);

  const int conv_blocks = B_SZ * BLK_PER_Z;   // 1152
  conv_kernel<<<conv_blocks, 256, 0, stream>>>(xyz, Z, emb, (const float*)nullptr,
                                               tabh0, f1, 1);
  conv_kernel<<<conv_blocks, 256, 0, stream>>>(xyz, Z, emb, f1,
                                               tabh1, f2, 0);

  pool_kernel<<<B_SZ, 256, 0, stream>>>(f1, f2, pool_sq);

  tail_kernel<<<1, 512, 0, stream>>>(pool_sq, fc_w, fc_b, bn_g, bn_b,
                                     out_w, out_b, out);
}